// Round 3
// baseline (127.618 us; speedup 1.0000x reference)
//
#include <hip/hip_runtime.h>

#define S_LEN 4096
#define BATCH 2
#define DM 512
#define NH 8
#define DH 64
#define WINDOW 256

typedef __bf16 bf16x8 __attribute__((ext_vector_type(8)));
typedef float f32x4 __attribute__((ext_vector_type(4)));

typedef const __attribute__((address_space(1))) unsigned int* gas_ptr;
typedef __attribute__((address_space(3))) unsigned int* las_ptr;

#define SCALE_LOG2E 0.1803368801111204f  // 0.125 * log2(e)
#define FIXED_MAX 16.0f                  // safe upper bound for log2-domain scores

// Raw barrier without the compiler's vmcnt(0)/lgkmcnt(0) drain; the ""::memory
// asms pin compiler memory-op ordering across it (s_barrier intrinsic alone is
// not a compiler memory fence).
#define BAR()                                   \
  do {                                          \
    asm volatile("" ::: "memory");              \
    __builtin_amdgcn_s_barrier();               \
    asm volatile("" ::: "memory");              \
  } while (0)
#define WAITVM(N) asm volatile("s_waitcnt vmcnt(" #N ")" ::: "memory")

// native gfx950 bf16 convert, RNE
__device__ __forceinline__ unsigned short b16(float f) {
  __bf16 h = (__bf16)f;
  return __builtin_bit_cast(unsigned short, h);
}

// One fused fp32->bf16 convert for x, qkv_w, out_w (contiguous dest regions).
#define N4_X (8192 * 512 / 4)
#define N4_QW (1536 * 512 / 4)
#define N4_OW (512 * 512 / 4)
__global__ __launch_bounds__(256) void convert_all(const float* __restrict__ x,
                                                   const float* __restrict__ qw,
                                                   const float* __restrict__ ow,
                                                   unsigned short* __restrict__ dst) {
  const int i = blockIdx.x * blockDim.x + threadIdx.x;  // exact grid, one float4 each
  const float4* src;
  int off;
  if (i < N4_X) { src = (const float4*)x; off = 0; }
  else if (i < N4_X + N4_QW) { src = (const float4*)qw; off = N4_X; }
  else { src = (const float4*)ow; off = N4_X + N4_QW; }
  const float4 v = src[i - off];
  ushort4 o;
  o.x = b16(v.x); o.y = b16(v.y); o.z = b16(v.z); o.w = b16(v.w);
  ((ushort4*)dst)[i] = o;
}

// 2-phase double-buffered K-loop (T3-minimum): C128x128 = A[128x512]*B[128x512]^T,
// BK=32, global_load_lds width-16 staging prefetched one iter ahead, counted
// vmcnt (never 0 mid-loop), raw barriers (no full drain). 16x16x32 MFMA, 4 waves.
__device__ __forceinline__ void gemm_core(const unsigned short* __restrict__ A,
                                          const unsigned short* __restrict__ Bm,
                                          int m0, int n0,
                                          unsigned short* sA, unsigned short* sB,
                                          f32x4 acc[4][4]) {
  const int t = threadIdx.x;
  const int wave = t >> 6, lane = t & 63;
  const int wr = wave >> 1, wc = wave & 1;
  const int quad = lane >> 4, l16 = lane & 15;

#define QKV_STAGE(k0, buf)                                                       \
  do {                                                                           \
    _Pragma("unroll") for (int p = 0; p < 2; ++p) {                              \
      const int ci = wave * 128 + p * 64 + lane;                                 \
      const int row = ci >> 2, cg = ci & 3;                                      \
      const unsigned short* ga = A + (size_t)(m0 + row) * 512 + (k0) + cg * 8;   \
      __builtin_amdgcn_global_load_lds(                                          \
          (gas_ptr)(const void*)ga,                                              \
          (las_ptr)(void*)(sA + (buf) * 4096 + wave * 1024 + p * 512), 16, 0, 0);\
      const unsigned short* gb = Bm + (size_t)(n0 + row) * 512 + (k0) + cg * 8;  \
      __builtin_amdgcn_global_load_lds(                                          \
          (gas_ptr)(const void*)gb,                                              \
          (las_ptr)(void*)(sB + (buf) * 4096 + wave * 1024 + p * 512), 16, 0, 0);\
    }                                                                            \
  } while (0)

  QKV_STAGE(0, 0);
  for (int k0 = 0; k0 < 512; k0 += 32) {
    const int cur = (k0 >> 5) & 1;
    BAR();  // all waves done reading buf[cur^1] -> safe to overwrite it
    if (k0 + 32 < 512) {
      QKV_STAGE(k0 + 32, cur ^ 1);
      WAITVM(4);  // my buf[cur] loads (issued last iter) have landed
    } else {
      WAITVM(0);
    }
    BAR();  // everyone's buf[cur] staged
    const unsigned short* bA = sA + cur * 4096;
    const unsigned short* bB = sB + cur * 4096;
    bf16x8 af[4], bff[4];
#pragma unroll
    for (int i = 0; i < 4; ++i)
      af[i] = *(const bf16x8*)&bA[(wr * 64 + i * 16 + l16) * 32 + quad * 8];
#pragma unroll
    for (int j = 0; j < 4; ++j)
      bff[j] = *(const bf16x8*)&bB[(wc * 64 + j * 16 + l16) * 32 + quad * 8];
#pragma unroll
    for (int i = 0; i < 4; ++i)
#pragma unroll
      for (int j = 0; j < 4; ++j)
        acc[i][j] = __builtin_amdgcn_mfma_f32_16x16x32_bf16(af[i], bff[j], acc[i][j], 0, 0, 0);
  }
#undef QKV_STAGE
}

// QKV projection, 128x128 tile, XCD-pinned 1D swizzle (R17 win): id%8 = XCD,
// each XCD runs one row-block's 12 column-blocks consecutively -> A-tile and
// whole B matrix (1.5 MB) L2-resident per XCD.
__global__ __launch_bounds__(256) void gemm_qkv(const unsigned short* __restrict__ xb,
                                                const unsigned short* __restrict__ wb,
                                                const float* __restrict__ bias,
                                                unsigned short* __restrict__ Qb,
                                                unsigned short* __restrict__ Kb,
                                                unsigned short* __restrict__ Vt) {
  __shared__ __align__(16) unsigned short sA[2 * 128 * 32];
  __shared__ __align__(16) unsigned short sB[2 * 128 * 32];
  f32x4 acc[4][4] = {};
  const int id = blockIdx.x;
  const int X = id & 7;          // XCD slot
  const int t2 = id >> 3;
  const int cb = t2 % 12;        // column block 0..11
  const int rb = (t2 / 12) * 8 + X;  // row block 0..63, pinned to XCD X
  const int m0 = rb * 128, n0 = cb * 128;
  gemm_core(xb, wb, m0, n0, sA, sB, acc);

  const int t = threadIdx.x;
  const int wave = t >> 6, lane = t & 63;
  const int wr = wave >> 1, wc = wave & 1;
  const int quad = lane >> 4, l16 = lane & 15;
#pragma unroll
  for (int j = 0; j < 4; ++j) {
    const int n = n0 + wc * 64 + j * 16 + l16;
    const float bv = bias[n];
#pragma unroll
    for (int i = 0; i < 4; ++i) {
      const int mr = m0 + wr * 64 + i * 16 + quad * 4;
      if (n < DM) {
#pragma unroll
        for (int r = 0; r < 4; ++r)
          Qb[(size_t)(mr + r) * DM + n] = b16((acc[i][j][r] + bv) * SCALE_LOG2E);
      } else if (n < 2 * DM) {
#pragma unroll
        for (int r = 0; r < 4; ++r)
          Kb[(size_t)(mr + r) * DM + (n - DM)] = b16(acc[i][j][r] + bv);
      } else {
        const int d = n & 63, h = (n - 2 * DM) >> 6;
#pragma unroll
        for (int r = 0; r < 4; ++r) {
          const int m = mr + r;
          const int b = m >> 12, s = m & (S_LEN - 1);
          Vt[((size_t)((b * NH + h) * DH + d)) * S_LEN + s] = b16(acc[i][j][r] + bv);
        }
      }
    }
  }
}

// Output projection, 64x128 tile, BK=32, 1D grid 512 with XCD-pinned swizzle
// (R18 win): id%8 = XCD, wout (512 KB) L2-resident per XCD. Same 2-phase pipe.
__global__ __launch_bounds__(256) void gemm_out(const unsigned short* __restrict__ Ab,
                                                const unsigned short* __restrict__ wb,
                                                const float* __restrict__ bias,
                                                float* __restrict__ C) {
  __shared__ __align__(16) unsigned short sA[2 * 64 * 32];
  __shared__ __align__(16) unsigned short sB[2 * 128 * 32];
  const int t = threadIdx.x;
  const int wave = t >> 6, lane = t & 63;
  const int wr = wave >> 1, wc = wave & 1;
  const int quad = lane >> 4, l16 = lane & 15;
  const int id = blockIdx.x;
  const int X = id & 7;              // XCD slot
  const int t2 = id >> 3;
  const int cb = t2 % 4;             // column block 0..3
  const int rb = (t2 / 4) * 8 + X;   // row block 0..127, pinned to XCD X
  const int m0 = rb * 64, n0 = cb * 128;

#define OUT_STAGE(k0, buf)                                                       \
  do {                                                                           \
    {                                                                            \
      const int row = t >> 2, cg = t & 3;                                        \
      const unsigned short* ga = Ab + (size_t)(m0 + row) * 512 + (k0) + cg * 8;  \
      __builtin_amdgcn_global_load_lds(                                          \
          (gas_ptr)(const void*)ga,                                              \
          (las_ptr)(void*)(sA + (buf) * 2048 + wave * 512), 16, 0, 0);           \
    }                                                                            \
    _Pragma("unroll") for (int p = 0; p < 2; ++p) {                              \
      const int ci = wave * 128 + p * 64 + lane;                                 \
      const int row = ci >> 2, cg = ci & 3;                                      \
      const unsigned short* gb = wb + (size_t)(n0 + row) * 512 + (k0) + cg * 8;  \
      __builtin_amdgcn_global_load_lds(                                          \
          (gas_ptr)(const void*)gb,                                              \
          (las_ptr)(void*)(sB + (buf) * 4096 + wave * 1024 + p * 512), 16, 0, 0);\
    }                                                                            \
  } while (0)

  f32x4 acc[2][4] = {};
  OUT_STAGE(0, 0);
  for (int k0 = 0; k0 < 512; k0 += 32) {
    const int cur = (k0 >> 5) & 1;
    BAR();
    if (k0 + 32 < 512) {
      OUT_STAGE(k0 + 32, cur ^ 1);
      WAITVM(3);
    } else {
      WAITVM(0);
    }
    BAR();
    const unsigned short* bA = sA + cur * 2048;
    const unsigned short* bB = sB + cur * 4096;
    bf16x8 af[2], bff[4];
#pragma unroll
    for (int i = 0; i < 2; ++i)
      af[i] = *(const bf16x8*)&bA[(wr * 32 + i * 16 + l16) * 32 + quad * 8];
#pragma unroll
    for (int j = 0; j < 4; ++j)
      bff[j] = *(const bf16x8*)&bB[(wc * 64 + j * 16 + l16) * 32 + quad * 8];
#pragma unroll
    for (int i = 0; i < 2; ++i)
#pragma unroll
      for (int j = 0; j < 4; ++j)
        acc[i][j] = __builtin_amdgcn_mfma_f32_16x16x32_bf16(af[i], bff[j], acc[i][j], 0, 0, 0);
  }
#undef OUT_STAGE

#pragma unroll
  for (int j = 0; j < 4; ++j) {
    const int n = n0 + wc * 64 + j * 16 + l16;
    const float bv = bias[n];
#pragma unroll
    for (int i = 0; i < 2; ++i) {
      const int mr = m0 + wr * 32 + i * 16 + quad * 4;
#pragma unroll
      for (int r = 0; r < 4; ++r)
        C[(size_t)(mr + r) * DM + n] = acc[i][j][r] + bv;
    }
  }
}

// MFMA flash attention. K/V staged by global_load_lds into XOR-swizzled
// double-buffered LDS (rule #21 both-sides swizzle: linear LDS dest,
// inverse-swizzled per-lane GLOBAL source, swizzled ds_read addr), raw
// barriers + counted vmcnt so the next chunk's DMA flies under this chunk's
// QK/softmax/PV. Eliminates the reg round-trip (kbuf/vbuf + 4 ds_write_b128
// per thread per chunk) whose prefetch was defeated by __syncthreads' vmcnt(0)
// drain. Ps uses the same XOR scheme (64-stride) -> LDS exactly 40 KB = 4
// blocks/CU.
__global__ __launch_bounds__(256) void attn_mfma(const unsigned short* __restrict__ Qb,
                                                 const unsigned short* __restrict__ Kb,
                                                 const unsigned short* __restrict__ Vt,
                                                 unsigned short* __restrict__ AO) {
  __shared__ __align__(16) unsigned short Ks[2 * 64 * 64];
  __shared__ __align__(16) unsigned short Vs[2 * 64 * 64];  // V^T chunk: [d][seq]
  __shared__ __align__(16) unsigned short Ps[64 * 64];      // P: [query][key], XOR-swizzled
  const int t = threadIdx.x;
  const int wave = t >> 6, lane = t & 63;
  const int quad = lane >> 4, l16 = lane & 15;

  // decode swizzled id: X = xcd slot, o = tile within group, h = head, b
  const int id = blockIdx.x;
  const int X = id & 7;
  const int o = (id >> 3) & 7;
  const int h = (id >> 6) & 7;
  const int b = id >> 9;
  const int g = (X - h) & 7;          // group of 8 q-tiles pinned to XCD X
  const int qt = g * 8 + o;           // q-tile index 0..63
  const int q0 = qt * 64;

  const unsigned short* Kbase = Kb + (size_t)b * S_LEN * DM + h * DH;
  const unsigned short* Vbase = Vt + (size_t)((b * NH + h) * DH) * S_LEN;

  // Q fragments from global, loop-invariant (pre-scaled by SCALE_LOG2E).
  const unsigned short* qrow =
      Qb + (size_t)(b * S_LEN + q0 + wave * 16 + l16) * DM + h * DH;
  const bf16x8 aq0 = *(const bf16x8*)(qrow + quad * 8);
  const bf16x8 aq1 = *(const bf16x8*)(qrow + 32 + quad * 8);

  const int first = (qt >= 4) ? 0 : (4 - qt);  // first valid chunk

  // Staging geometry: LDS slot L (0..511, 16B chunks) holds the global 16B
  // chunk (row = L>>3, c = (L&7) ^ (row&7)). Thread t fills slots t and t+256.
  int grow[2], gcol[2];
#pragma unroll
  for (int s = 0; s < 2; ++s) {
    const int L = t + 256 * s;
    grow[s] = L >> 3;
    gcol[s] = ((L & 7) ^ (grow[s] & 7)) * 8;
  }

#define ATTN_STAGE(c0, buf)                                                       \
  do {                                                                            \
    _Pragma("unroll") for (int s = 0; s < 2; ++s) {                               \
      const unsigned short* gk = Kbase + (size_t)((c0) + grow[s]) * DM + gcol[s]; \
      __builtin_amdgcn_global_load_lds(                                           \
          (gas_ptr)(const void*)gk,                                               \
          (las_ptr)(void*)(Ks + (buf) * 4096 + wave * 512 + s * 2048), 16, 0, 0); \
      const unsigned short* gv = Vbase + (size_t)grow[s] * S_LEN + (c0) + gcol[s];\
      __builtin_amdgcn_global_load_lds(                                           \
          (gas_ptr)(const void*)gv,                                               \
          (las_ptr)(void*)(Vs + (buf) * 4096 + wave * 512 + s * 2048), 16, 0, 0); \
    }                                                                             \
  } while (0)

  ATTN_STAGE(q0 - WINDOW + first * 64, first & 1);

  float l_ = 0.f;       // scalar: all of this lane's P values share query l16
  f32x4 O[4] = {};      // O^T: row = d = nt*16+quad*4+r, col = query = l16

  const int sw = l16 & 7;              // row-XOR (row & 7 == l16 & 7 for all frags)
  const int c0q = (quad ^ sw) * 8;     // swizzled ushort offset, chunks 0..3
  const int c1q = ((quad | 4) ^ sw) * 8;  // swizzled ushort offset, chunks 4..7

#pragma unroll
  for (int c = 0; c < 5; ++c) {
    if (c < first) continue;  // block-uniform
    const int c0 = q0 - WINDOW + c * 64;
    const int cur = c & 1;
    BAR();  // all waves done reading buf[cur^1] -> safe to overwrite
    if (c < 4) {
      ATTN_STAGE(c0 + 64, cur ^ 1);  // prefetch next chunk under this compute
      WAITVM(4);                     // chunk-c DMA (issued last iter) landed
    } else {
      WAITVM(0);
    }
    BAR();  // everyone's chunk-c staged

    const unsigned short* Kc = Ks + cur * 4096;
    const unsigned short* Vc = Vs + cur * 4096;

    // S^T = K Q^T: A = K-frag (rows = keys), B = Q-frag (cols = queries)
    f32x4 sc[4];
#pragma unroll
    for (int nt = 0; nt < 4; ++nt) {
      const int krow = (nt * 16 + l16) * 64;
      bf16x8 bk0 = *(const bf16x8*)&Kc[krow + c0q];
      bf16x8 bk1 = *(const bf16x8*)&Kc[krow + c1q];
      f32x4 z = {};
      z = __builtin_amdgcn_mfma_f32_16x16x32_bf16(bk0, aq0, z, 0, 0, 0);
      sc[nt] = __builtin_amdgcn_mfma_f32_16x16x32_bf16(bk1, aq1, z, 0, 0, 0);
    }

    // p = exp2(s - 16); boundary masks with key/query roles per S^T layout.
    const int iiq = wave * 16 + l16;  // query (local)
    const int prow = iiq * 64;
#pragma unroll
    for (int nt = 0; nt < 4; ++nt) {
#pragma unroll
      for (int r = 0; r < 4; ++r) {
        const int jjk = nt * 16 + quad * 4 + r;  // key (local)
        float p = exp2f(sc[nt][r] - FIXED_MAX);
        if (c == 0) p = (jjk >= iiq) ? p : 0.f;
        if (c == 4) p = (jjk <= iiq) ? p : 0.f;
        sc[nt][r] = p;
        l_ += p;
      }
      ushort4 pk;
      pk.x = b16(sc[nt][0]);
      pk.y = b16(sc[nt][1]);
      pk.z = b16(sc[nt][2]);
      pk.w = b16(sc[nt][3]);
      // key chunk = nt*2 + (quad>>1), swizzled by row (iiq&7 == sw); 8B write.
      *(ushort4*)&Ps[prow + (((nt * 2 + (quad >> 1)) ^ sw) * 8) + (quad & 1) * 4] = pk;
    }

    // B-frags of P^T: lane (quad,l16) reads own row iiq, key chunks quad / quad+4
    // (wave-private rows: no barrier needed, same as before).
    const bf16x8 bp0 = *(const bf16x8*)&Ps[prow + c0q];
    const bf16x8 bp1 = *(const bf16x8*)&Ps[prow + c1q];

    // O^T += V^T P^T: A = V^T frag (rows = d), B = P^T
#pragma unroll
    for (int nt = 0; nt < 4; ++nt) {
      const int vrow = (nt * 16 + l16) * 64;
      bf16x8 bv0 = *(const bf16x8*)&Vc[vrow + c0q];
      bf16x8 bv1 = *(const bf16x8*)&Vc[vrow + c1q];
      O[nt] = __builtin_amdgcn_mfma_f32_16x16x32_bf16(bv0, bp0, O[nt], 0, 0, 0);
      O[nt] = __builtin_amdgcn_mfma_f32_16x16x32_bf16(bv1, bp1, O[nt], 0, 0, 0);
    }
  }
#undef ATTN_STAGE

  // denominator: reduce partials across the 4 quads (lane bits 4,5)
  l_ += __shfl_xor(l_, 16);
  l_ += __shfl_xor(l_, 32);
  const float linv = 1.f / l_;

  // O^T C-layout: lane's 4 regs are d-consecutive -> packed 8B stores
  unsigned short* aoRow =
      AO + (size_t)(b * S_LEN + q0 + wave * 16 + l16) * DM + h * DH;
#pragma unroll
  for (int nt = 0; nt < 4; ++nt) {
    ushort4 o4;
    o4.x = b16(O[nt][0] * linv);
    o4.y = b16(O[nt][1] * linv);
    o4.z = b16(O[nt][2] * linv);
    o4.w = b16(O[nt][3] * linv);
    *(ushort4*)(aoRow + nt * 16 + quad * 4) = o4;
  }
}

extern "C" void kernel_launch(void* const* d_in, const int* in_sizes, int n_in,
                              void* d_out, int out_size, void* d_ws, size_t ws_size,
                              hipStream_t stream) {
  const float* x = (const float*)d_in[0];
  const float* qkv_w = (const float*)d_in[1];
  const float* qkv_b = (const float*)d_in[2];
  const float* out_w = (const float*)d_in[3];
  const float* out_b = (const float*)d_in[4];
  float* out = (float*)d_out;

  const int M = BATCH * S_LEN;  // 8192
  unsigned short* ws = (unsigned short*)d_ws;
  unsigned short* xb   = ws;                      // 8192*512
  unsigned short* wqkv = xb + (size_t)M * DM;     // 1536*512
  unsigned short* wout = wqkv + 3 * DM * DM;      // 512*512
  unsigned short* Qb   = wout + DM * DM;          // 8192*512
  unsigned short* Kb   = Qb + (size_t)M * DM;     // 8192*512
  unsigned short* Vt   = Kb + (size_t)M * DM;     // 2*8*64*4096
  unsigned short* AO   = Vt + (size_t)M * DM;     // 8192*512

  convert_all<<<(N4_X + N4_QW + N4_OW) / 256, 256, 0, stream>>>(x, qkv_w, out_w, xb);

  gemm_qkv<<<768, 256, 0, stream>>>(xb, wqkv, qkv_b, Qb, Kb, Vt);

  attn_mfma<<<1024, 256, 0, stream>>>(Qb, Kb, Vt, AO);

  gemm_out<<<512, 256, 0, stream>>>(AO, wout, out_b, out);
}